// Round 2
// baseline (698.603 us; speedup 1.0000x reference)
//
#include <hip/hip_runtime.h>
#include <math.h>

// Capsule dynamic routing, fully fused: one block of 512 threads per (b, c).
// B=256, C=10, N=1152, Din=8, U=16, 3 routing iterations.
// u_hat in registers: thread t owns u = (t&3)*4..+3, n = (t>>2) + 128k, k=0..8
// -> uh[9][4] = 36 floats/thread (prev 72 spilled at the 84-VGPR allocation;
//    this fits under the __launch_bounds__(512,4) cap of 128 VGPRs).

#define BATCH 256
#define CAPS  10
#define NIN   1152
#define DIN   8
#define UDIM  16
#define TPB   512
#define KITER 9    // NIN / (TPB/4)

__global__ __launch_bounds__(TPB, 4) void capsule_routing_kernel(
    const float* __restrict__ x,   // (B, N, Din)
    const float* __restrict__ W,   // (C, N, Din, U)
    float* __restrict__ out)       // (B, C, U)
{
    const int gblk = blockIdx.x;      // c-major for L2 W-locality
    const int c    = gblk >> 8;       // 0..9
    const int b    = gblk & 255;      // 0..255
    const int t    = threadIdx.x;     // 0..511
    const int ub   = (t & 3) << 2;    // u base: 0,4,8,12
    const int gg   = t >> 2;          // 0..127 (n residue)
    const int wave = t >> 6;          // 0..7

    __shared__ float x_s[NIN * DIN];  // 36 KB staged input row
    __shared__ float b_s[NIN];        // routing logits
    __shared__ float e_s[NIN];        // exp(b - max)
    __shared__ float redA[8];
    __shared__ float redB[8];
    __shared__ float ps[8][UDIM];     // per-wave partial s
    __shared__ float v_s[UDIM];       // squashed output vector

    // ---- stage x[b] into LDS (coalesced float4) ----
    {
        const float4* xg = (const float4*)(x + (size_t)b * (NIN * DIN));
        float4* xs = (float4*)x_s;
        for (int i = t; i < (NIN * DIN / 4); i += TPB)
            xs[i] = xg[i];
    }
    for (int n = t; n < NIN; n += TPB) b_s[n] = 1.0f;
    __syncthreads();

    // ---- compute u_hat into registers ----
    float uh[KITER][4];
    const float* Wc = W + (size_t)c * (NIN * DIN * UDIM);
    #pragma unroll
    for (int k = 0; k < KITER; ++k) {
        const int n = gg + 128 * k;
        const float4* wr = (const float4*)(Wc + n * (DIN * UDIM) + ub);
        const float4 x0 = ((const float4*)(x_s + n * DIN))[0];
        const float4 x1 = ((const float4*)(x_s + n * DIN))[1];
        float a0, a1, a2, a3;
        {
            float4 w = wr[0];
            a0 = x0.x * w.x; a1 = x0.x * w.y; a2 = x0.x * w.z; a3 = x0.x * w.w;
            w = wr[4];
            a0 += x0.y * w.x; a1 += x0.y * w.y; a2 += x0.y * w.z; a3 += x0.y * w.w;
            w = wr[8];
            a0 += x0.z * w.x; a1 += x0.z * w.y; a2 += x0.z * w.z; a3 += x0.z * w.w;
            w = wr[12];
            a0 += x0.w * w.x; a1 += x0.w * w.y; a2 += x0.w * w.z; a3 += x0.w * w.w;
            w = wr[16];
            a0 += x1.x * w.x; a1 += x1.x * w.y; a2 += x1.x * w.z; a3 += x1.x * w.w;
            w = wr[20];
            a0 += x1.y * w.x; a1 += x1.y * w.y; a2 += x1.y * w.z; a3 += x1.y * w.w;
            w = wr[24];
            a0 += x1.z * w.x; a1 += x1.z * w.y; a2 += x1.z * w.z; a3 += x1.z * w.w;
            w = wr[28];
            a0 += x1.w * w.x; a1 += x1.w * w.y; a2 += x1.w * w.z; a3 += x1.w * w.w;
        }
        uh[k][0] = a0; uh[k][1] = a1; uh[k][2] = a2; uh[k][3] = a3;
    }

    // ---- 3 routing iterations ----
    for (int it = 0; it < 3; ++it) {
        // block max of b_s (softmax stabilization)
        float m = -INFINITY;
        for (int n = t; n < NIN; n += TPB) m = fmaxf(m, b_s[n]);
        #pragma unroll
        for (int mk = 1; mk <= 32; mk <<= 1) m = fmaxf(m, __shfl_xor(m, mk));
        if ((t & 63) == 0) redA[wave] = m;
        __syncthreads();
        float bmax = redA[0];
        #pragma unroll
        for (int w = 1; w < 8; ++w) bmax = fmaxf(bmax, redA[w]);

        // exp + block sum
        float le = 0.f;
        for (int n = t; n < NIN; n += TPB) {
            const float e = expf(b_s[n] - bmax);
            e_s[n] = e;
            le += e;
        }
        #pragma unroll
        for (int mk = 1; mk <= 32; mk <<= 1) le += __shfl_xor(le, mk);
        if ((t & 63) == 0) redB[wave] = le;
        __syncthreads();
        float esum = redB[0];
        #pragma unroll
        for (int w = 1; w < 8; ++w) esum += redB[w];
        const float inv = 1.0f / esum;

        // s[u] = (sum_n e[n] * u_hat[n][u]) * inv
        float p0 = 0.f, p1 = 0.f, p2 = 0.f, p3 = 0.f;
        #pragma unroll
        for (int k = 0; k < KITER; ++k) {
            const float e = e_s[gg + 128 * k];
            p0 += e * uh[k][0]; p1 += e * uh[k][1];
            p2 += e * uh[k][2]; p3 += e * uh[k][3];
        }
        #pragma unroll
        for (int mk = 4; mk <= 32; mk <<= 1) {
            p0 += __shfl_xor(p0, mk); p1 += __shfl_xor(p1, mk);
            p2 += __shfl_xor(p2, mk); p3 += __shfl_xor(p3, mk);
        }
        if ((t & 63) < 4) {   // lanes 0..3 hold per-wave sums for ub = lane*4
            ps[wave][ub + 0] = p0; ps[wave][ub + 1] = p1;
            ps[wave][ub + 2] = p2; ps[wave][ub + 3] = p3;
        }
        __syncthreads();

        // squash on first 16 threads
        if (t < UDIM) {
            float s = 0.f;
            #pragma unroll
            for (int w = 0; w < 8; ++w) s += ps[w][t];
            s *= inv;
            float sq = s * s;
            #pragma unroll
            for (int mk = 1; mk <= 8; mk <<= 1) sq += __shfl_xor(sq, mk);
            const float scale = sq / ((1.0f + sq) * sqrtf(sq + 1e-9f));
            const float v = scale * s;
            v_s[t] = v;
            if (it == 2) out[((size_t)b * CAPS + c) * UDIM + t] = v;
        }
        __syncthreads();

        // b[n] += u_hat[n] . v
        if (it < 2) {
            #pragma unroll
            for (int k = 0; k < KITER; ++k) {
                float q = uh[k][0] * v_s[ub + 0] + uh[k][1] * v_s[ub + 1]
                        + uh[k][2] * v_s[ub + 2] + uh[k][3] * v_s[ub + 3];
                q += __shfl_xor(q, 1);
                q += __shfl_xor(q, 2);
                if ((t & 3) == 0) b_s[gg + 128 * k] += q;
            }
            __syncthreads();
        }
    }
}

extern "C" void kernel_launch(void* const* d_in, const int* in_sizes, int n_in,
                              void* d_out, int out_size, void* d_ws, size_t ws_size,
                              hipStream_t stream) {
    const float* x = (const float*)d_in[0];   // (256, 1152, 8)
    const float* W = (const float*)d_in[1];   // (10, 1152, 8, 16)
    float* out = (float*)d_out;               // (256, 10, 16)
    capsule_routing_kernel<<<BATCH * CAPS, TPB, 0, stream>>>(x, W, out);
}

// Round 3
// 130.279 us; speedup vs baseline: 5.3624x; 5.3624x over previous
//
#include <hip/hip_runtime.h>
#include <math.h>

// Capsule dynamic routing, fully fused: one block of 512 threads per (b, c).
// B=256, C=10, N=1152, Din=8, U=16, 3 routing iterations.
// u_hat lives in NINE NAMED float4 registers per thread (not an array — the
// array form spilled in rounds 1-2). Thread t owns u = (t&3)*4..+3,
// n = (t>>2) + 128k for k=0..8.
// __launch_bounds__(512, 1): min-occupancy demand of 1 wave/EU so the VGPR
// cap is high enough that nothing spills (rounds 1-2 proved an occupancy
// floor here forces a sub-live-set cap -> 74MB..1.3GB of scratch traffic).

#define BATCH 256
#define CAPS  10
#define NIN   1152
#define DIN   8
#define UDIM  16
#define TPB   512
#define KITER 9    // NIN / (TPB/4)

__global__ __launch_bounds__(TPB, 1) void capsule_routing_kernel(
    const float* __restrict__ x,   // (B, N, Din)
    const float* __restrict__ W,   // (C, N, Din, U)
    float* __restrict__ out)       // (B, C, U)
{
    const int gblk = blockIdx.x;      // c-major for L2 W-locality
    const int c    = gblk >> 8;       // 0..9
    const int b    = gblk & 255;      // 0..255
    const int t    = threadIdx.x;     // 0..511
    const int ub   = (t & 3) << 2;    // u base: 0,4,8,12
    const int gg   = t >> 2;          // 0..127 (n residue)
    const int wave = t >> 6;          // 0..7

    __shared__ float x_s[NIN * DIN];  // 36 KB staged input row
    __shared__ float b_s[NIN];        // routing logits
    __shared__ float redB[8];         // per-wave exp-sum partials
    __shared__ float ps[8][UDIM];     // per-wave partial s
    __shared__ float v_s[UDIM];       // squashed output vector

    // ---- stage x[b] into LDS (coalesced float4) ----
    {
        const float4* xg = (const float4*)(x + (size_t)b * (NIN * DIN));
        float4* xs = (float4*)x_s;
        #pragma unroll
        for (int i = 0; i < 5; ++i) {
            const int idx = t + TPB * i;
            if (idx < (NIN * DIN / 4)) xs[idx] = xg[idx];
        }
    }
    for (int n = t; n < NIN; n += TPB) b_s[n] = 1.0f;
    __syncthreads();

    const float* Wc = W + (size_t)c * (NIN * DIN * UDIM);

    // ---- compute u_hat into 9 named float4 registers ----
    float4 uh0, uh1, uh2, uh3, uh4, uh5, uh6, uh7, uh8;

#define UHCOMP(K, DST) { \
    const int n = gg + 128 * (K); \
    const float4* wr = (const float4*)(Wc + n * (DIN * UDIM) + ub); \
    const float4 xa = ((const float4*)(x_s + n * DIN))[0]; \
    const float4 xb = ((const float4*)(x_s + n * DIN))[1]; \
    float4 w0 = wr[0], w1 = wr[4], w2 = wr[8], w3 = wr[12]; \
    float4 acc; \
    acc.x = xa.x * w0.x + xa.y * w1.x + xa.z * w2.x + xa.w * w3.x; \
    acc.y = xa.x * w0.y + xa.y * w1.y + xa.z * w2.y + xa.w * w3.y; \
    acc.z = xa.x * w0.z + xa.y * w1.z + xa.z * w2.z + xa.w * w3.z; \
    acc.w = xa.x * w0.w + xa.y * w1.w + xa.z * w2.w + xa.w * w3.w; \
    w0 = wr[16]; w1 = wr[20]; w2 = wr[24]; w3 = wr[28]; \
    acc.x += xb.x * w0.x + xb.y * w1.x + xb.z * w2.x + xb.w * w3.x; \
    acc.y += xb.x * w0.y + xb.y * w1.y + xb.z * w2.y + xb.w * w3.y; \
    acc.z += xb.x * w0.z + xb.y * w1.z + xb.z * w2.z + xb.w * w3.z; \
    acc.w += xb.x * w0.w + xb.y * w1.w + xb.z * w2.w + xb.w * w3.w; \
    DST = acc; } \
    __builtin_amdgcn_sched_barrier(0);

    UHCOMP(0, uh0)
    UHCOMP(1, uh1)
    UHCOMP(2, uh2)
    UHCOMP(3, uh3)
    UHCOMP(4, uh4)
    UHCOMP(5, uh5)
    UHCOMP(6, uh6)
    UHCOMP(7, uh7)
    UHCOMP(8, uh8)

    // ---- 3 routing iterations ----
    for (int it = 0; it < 3; ++it) {
        // e = exp(b) (no max-shift: b stays within ~1 +/- 0.5, exp is safe;
        // softmax is shift-invariant). Each n's exp computed by the 4 threads
        // that own it -> denominator partials counted 4x, divide by 4 later.
        float le = 0.f;
        float4 p; p.x = p.y = p.z = p.w = 0.f;

#define ACCP(K, UH) { \
        const float e = expf(b_s[gg + 128 * (K)]); \
        le += e; \
        p.x += e * UH.x; p.y += e * UH.y; p.z += e * UH.z; p.w += e * UH.w; }

        ACCP(0, uh0) ACCP(1, uh1) ACCP(2, uh2)
        ACCP(3, uh3) ACCP(4, uh4) ACCP(5, uh5)
        ACCP(6, uh6) ACCP(7, uh7) ACCP(8, uh8)

        // wave-reduce le (full 64 lanes)
        #pragma unroll
        for (int mk = 1; mk <= 32; mk <<= 1) le += __shfl_xor(le, mk);
        if ((t & 63) == 0) redB[wave] = le;

        // wave-reduce p over the 16 gg-groups (lanes differing in bits 2..5)
        #pragma unroll
        for (int mk = 4; mk <= 32; mk <<= 1) {
            p.x += __shfl_xor(p.x, mk); p.y += __shfl_xor(p.y, mk);
            p.z += __shfl_xor(p.z, mk); p.w += __shfl_xor(p.w, mk);
        }
        if ((t & 63) < 4) {   // lanes 0..3 hold wave sums for ub = lane*4
            ps[wave][ub + 0] = p.x; ps[wave][ub + 1] = p.y;
            ps[wave][ub + 2] = p.z; ps[wave][ub + 3] = p.w;
        }
        __syncthreads();

        // squash on first 16 threads
        if (t < UDIM) {
            float esum = 0.f;
            #pragma unroll
            for (int w = 0; w < 8; ++w) esum += redB[w];
            const float inv = 4.0f / esum;   // 4x overcount
            float s = 0.f;
            #pragma unroll
            for (int w = 0; w < 8; ++w) s += ps[w][t];
            s *= inv;
            float sq = s * s;
            #pragma unroll
            for (int mk = 1; mk <= 8; mk <<= 1) sq += __shfl_xor(sq, mk);
            const float scale = sq / ((1.0f + sq) * sqrtf(sq + 1e-9f));
            const float v = scale * s;
            v_s[t] = v;
            if (it == 2) out[((size_t)b * CAPS + c) * UDIM + t] = v;
        }
        __syncthreads();

        // b[n] += u_hat[n] . v
        if (it < 2) {
            const float4 v4 = *(const float4*)(v_s + ub);

#define BUPD(K, UH) { \
            float q = UH.x * v4.x + UH.y * v4.y + UH.z * v4.z + UH.w * v4.w; \
            q += __shfl_xor(q, 1); \
            q += __shfl_xor(q, 2); \
            if ((t & 3) == 0) b_s[gg + 128 * (K)] += q; }

            BUPD(0, uh0) BUPD(1, uh1) BUPD(2, uh2)
            BUPD(3, uh3) BUPD(4, uh4) BUPD(5, uh5)
            BUPD(6, uh6) BUPD(7, uh7) BUPD(8, uh8)
            __syncthreads();
        }
    }
}

extern "C" void kernel_launch(void* const* d_in, const int* in_sizes, int n_in,
                              void* d_out, int out_size, void* d_ws, size_t ws_size,
                              hipStream_t stream) {
    const float* x = (const float*)d_in[0];   // (256, 1152, 8)
    const float* W = (const float*)d_in[1];   // (10, 1152, 8, 16)
    float* out = (float*)d_out;               // (256, 10, 16)
    capsule_routing_kernel<<<BATCH * CAPS, TPB, 0, stream>>>(x, W, out);
}